// Round 6
// baseline (152.688 us; speedup 1.0000x reference)
//
#include <hip/hip_runtime.h>
#include <math.h>

// Problem constants
#define TT 8
#define BB 128
#define GG 256
#define DD 64
#define NCH 4     // D chunks
#define CF4 4     // float4s per cell per chunk (16 floats)
#define ST 5      // padded LDS stride in float4s -- MEASURED zero-conflict (rounds 0,4).
                  // Round-5 lesson: do NOT replace with derived swizzles (XOR-q "perfect
                  // spread" measured 2.24M conflicts). Trust the measured layout.

// ws layout: ws[pair*8 + c], c: 0 zdiff, 1 pres, 2 poolc(neg), 3 obj,
//                               4 flow_sq, 5 sum(zp), 6 sum(flow), 7 unused
// Round-2 lesson: contended device atomics in the block epilogue cost ~15 us;
// private ws slots + 1-block final_kernel is strictly better.

__device__ inline float wred(float v) {
#pragma unroll
    for (int off = 32; off > 0; off >>= 1) v += __shfl_xor(v, off, 64);
    return v;
}
__device__ inline float dot4(float4 a, float4 b) {
    return a.x * b.x + a.y * b.y + a.z * b.z + a.w * b.w;
}
__device__ inline float4 fabs4(float4 a) {
    return make_float4(fabsf(a.x), fabsf(a.y), fabsf(a.z), fabsf(a.w));
}
__device__ inline float4 max4(float4 a, float4 b) {
    return make_float4(fmaxf(a.x, b.x), fmaxf(a.y, b.y), fmaxf(a.z, b.z), fmaxf(a.w, b.w));
}
__device__ inline float4 scale4(float4 a, float s) {
    return make_float4(a.x * s, a.y * s, a.z * s, a.w * s);
}
__device__ inline float4 sub4(float4 a, float4 b) {
    return make_float4(a.x - b.x, a.y - b.y, a.z - b.z, a.w - b.w);
}

// ---- DPP row rotations (16-lane rows == grid rows, since cell == tid) ----
// ROW_ROR:N rotates within each 16-lane row WITH wraparound == jnp.roll on gj.
// Direction convention (does ror:1 fetch gj+1 or gj-1?) is made irrelevant by
// construction: the neighbor COLUMN INDEX is computed by applying the same
// rotation to gj itself, so every rotated dot is paired with the matching
// neighbor's norm/presence. ror1 and ror15 are the two opposite unit rotations.
#define DPP_ROR1  0x121
#define DPP_ROR15 0x12F
template <int CTRL>
__device__ inline int dppi(int v) {
    return __builtin_amdgcn_update_dpp(v, v, CTRL, 0xF, 0xF, false);
}
template <int CTRL>
__device__ inline float dppf(float v) {
    return __int_as_float(dppi<CTRL>(__float_as_int(v)));
}
template <int CTRL>
__device__ inline float4 dpp4(float4 v) {
    return make_float4(dppf<CTRL>(v.x), dppf<CTRL>(v.y), dppf<CTRL>(v.z), dppf<CTRL>(v.w));
}

// 3-wide clamped row max via DPP (verified rounds 1-4). old = v, bound_ctrl=false
// -> out-of-row lanes get v (identity for max): clamped semantics for free.
__device__ inline float rowmax3(float v) {
    int iv = __float_as_int(v);
    int a = __builtin_amdgcn_update_dpp(iv, iv, 0x101, 0xF, 0xF, false); // row_shl:1
    int c = __builtin_amdgcn_update_dpp(iv, iv, 0x111, 0xF, 0xF, false); // row_shr:1
    return fmaxf(v, fmaxf(__int_as_float(a), __int_as_float(c)));
}
__device__ inline float4 rowmax3_4(float4 v) {
    return make_float4(rowmax3(v.x), rowmax3(v.y), rowmax3(v.z), rowmax3(v.w));
}

// VGPR budget notes (rounds 1/3/5): never pass a min-waves arg (",4" -> 64 VGPR ->
// 326 MB spill); no register prefetch and no hoisted epilogue loads (both pushed
// past the 128 cliff -> 3 waves/SIMD, ~ -24 us). Target <= 128.
__global__ __launch_bounds__(256) void pair_kernel(const float* __restrict__ zw,
                                                   const float* __restrict__ zp,
                                                   const float* __restrict__ flow,
                                                   float* __restrict__ ws) {
    const int pairIdx = blockIdx.x;            // 0 .. 7*BB-1
    const int t = pairIdx >> 7;                // BB = 128
    const int b = pairIdx & (BB - 1);
    const int tid = threadIdx.x;
    const int gi = tid >> 4, gj = tid & 15;

    __shared__ float4 shB[GG * ST];            // raw B chunk (up/down neighbor rows)
    __shared__ float4 shM[GG * ST];            // row-max chunk (col-max pass)
    __shared__ float pA[GG], pB[GG], nrmB[GG];
    __shared__ float bred[7][4];

    const float4* gA = (const float4*)zw + (size_t)(t * BB + b) * 1024;
    const float4* gB = gA + (size_t)BB * 1024;

    const float pAc = zp[(size_t)(t * BB + b) * GG + tid];
    const float pBc = zp[(size_t)((t + 1) * BB + b) * GG + tid];
    pA[tid] = pAc;                             // visibility covered by chunk-loop syncs
    pB[tid] = pBc;

    // neighbor columns, derived with the SAME rotations as the data (direction-proof)
    const int ncol1 = dppi<DPP_ROR1>(gj);
    const int ncol2 = dppi<DPP_ROR15>(gj);
    const int rowU = ((gi - 1) & 15) << 4;     // wrapped up-row base cell
    const int rowD = ((gi + 1) & 15) << 4;     // wrapped down-row base cell
    const int baseU = (rowU + gj) * ST;
    const int baseD = (rowD + gj) * ST;

    // dots d<r><c>: r 0=up,1=center,2=down ; c 0=own col, 1=ror1 col, 2=ror15 col
    float d00 = 0.f, d01 = 0.f, d02 = 0.f;
    float d10 = 0.f, d11 = 0.f, d12 = 0.f;
    float d20 = 0.f, d21 = 0.f, d22 = 0.f;
    float zdiff = 0.f, sa = 0.f, sb = 0.f, poolDot = 0.f, poolN = 0.f;
    const int sbase = tid * ST;

    // IMPORTANT: unroll 1 -- full unroll hoists all chunks' global loads and spills.
#pragma unroll 1
    for (int c = 0; c < NCH; c++) {
        float4 aA[CF4], aB[CF4];
#pragma unroll
        for (int q = 0; q < CF4; q++) {
            aA[q] = gA[tid * 16 + c * 4 + q];
            aB[q] = gB[tid * 16 + c * 4 + q];
        }

        // stage raw B and DPP row-max into separate buffers -> one sync serves both
        float4 rm[CF4];
#pragma unroll
        for (int q = 0; q < CF4; q++) {
            shB[sbase + q] = aB[q];
            rm[q] = rowmax3_4(scale4(fabs4(aA[q]), pAc));
            shM[sbase + q] = rm[q];
        }
        // center row entirely from registers: stats + 3 dots (own, ror1, ror15)
#pragma unroll
        for (int q = 0; q < CF4; q++) {
            float4 d = sub4(aB[q], aA[q]);
            zdiff += dot4(d, d);
            sa += dot4(aA[q], aA[q]);
            sb += dot4(aB[q], aB[q]);
            d10 += dot4(aA[q], aB[q]);
            d11 += dot4(aA[q], dpp4<DPP_ROR1>(aB[q]));
            d12 += dot4(aA[q], dpp4<DPP_ROR15>(aB[q]));
        }
        __syncthreads();

        // up/down rows: ONE LDS read each per q, columns via DPP rotation
        // (replaces 6 of the 8 neighbor LDS read-sets of round 4)
#pragma unroll
        for (int q = 0; q < CF4; q++) {
            float4 bu = shB[baseU + q];
            d00 += dot4(aA[q], bu);
            d01 += dot4(aA[q], dpp4<DPP_ROR1>(bu));
            d02 += dot4(aA[q], dpp4<DPP_ROR15>(bu));
            float4 bd = shB[baseD + q];
            d20 += dot4(aA[q], bd);
            d21 += dot4(aA[q], dpp4<DPP_ROR1>(bd));
            d22 += dot4(aA[q], dpp4<DPP_ROR15>(bd));
        }
        // clamped col-max of row-max (in place on rm), then pool accumulation
        if (gi > 0) {
            const int base = (tid - 16) * ST;
#pragma unroll
            for (int q = 0; q < CF4; q++) rm[q] = max4(rm[q], shM[base + q]);
        }
        if (gi < 15) {
            const int base = (tid + 16) * ST;
#pragma unroll
            for (int q = 0; q < CF4; q++) rm[q] = max4(rm[q], shM[base + q]);
        }
#pragma unroll
        for (int q = 0; q < CF4; q++) {
            poolDot += dot4(rm[q], fabs4(aB[q]));
            poolN += dot4(rm[q], rm[q]);
        }
        __syncthreads();   // all reads of shB/shM done before next chunk's stores
    }

    // ---- epilogues ----
    nrmB[tid] = sqrtf(sb);
    __syncthreads();

    // objects: 9 (dot, neighbor-cell) pairs, pairing guaranteed by shared rotations
    const int gcol = gi << 4;
    const int ncell[9] = {rowU + gj, rowU + ncol1, rowU + ncol2,
                          tid,       gcol + ncol1, gcol + ncol2,
                          rowD + gj, rowD + ncol1, rowD + ncol2};
    const float dval[9] = {d00, d01, d02, d10, d11, d12, d20, d21, d22};
    float prior_n = fmaxf(sqrtf(sa), 1e-8f);
    float sum_sim = 0.f, max_sim = -1e30f;
    bool has = false;
#pragma unroll
    for (int k = 0; k < 9; k++) {
        float nn = fmaxf(nrmB[ncell[k]], 1e-8f);
        float s = dval[k] / (prior_n * nn);
        if (pB[ncell[k]] > 0.5f) {
            sum_sim += s;
            max_sim = fmaxf(max_sim, s);
            has = true;
        }
    }
    float obj = ((pAc > 0.5f) && has) ? (sum_sim - 5.0f * max_sim) : 0.f;

    // pool
    float na_pool = fmaxf(sqrtf(poolN), 1e-6f);
    float nb_pool = fmaxf(pBc * sqrtf(sb), 1e-6f);
    float poolc = -(pBc * poolDot) / (na_pool * nb_pool) * 0.5f * (pAc + pBc);

    // flow (image t; block t=6 also handles image 7): clamped 3x3 max of zp
    float mx = pAc;
#pragma unroll
    for (int di = -1; di <= 1; di++)
#pragma unroll
        for (int dj = -1; dj <= 1; dj++) {
            if (di == 0 && dj == 0) continue;
            int ni = gi + di, nj = gj + dj;
            if (((unsigned)ni < 16u) && ((unsigned)nj < 16u))
                mx = fmaxf(mx, pA[(ni << 4) + nj]);
        }
    float f = flow[(size_t)(t * BB + b) * GG + tid];
    float fsq = 0.f;
    if (f > 0.5f) { float d = mx - f; fsq = d * d; }
    float szp = pAc, sflow = f;
    if (t == 6) {
        float mxB = pBc;
#pragma unroll
        for (int di = -1; di <= 1; di++)
#pragma unroll
            for (int dj = -1; dj <= 1; dj++) {
                if (di == 0 && dj == 0) continue;
                int ni = gi + di, nj = gj + dj;
                if (((unsigned)ni < 16u) && ((unsigned)nj < 16u))
                    mxB = fmaxf(mxB, pB[(ni << 4) + nj]);
            }
        float f7 = flow[(size_t)(7 * BB + b) * GG + tid];
        if (f7 > 0.5f) { float d = mxB - f7; fsq += d * d; }
        szp += pBc;
        sflow += f7;
    }

    // pres triple (t, t+1, t+2) for t <= 5
    float pres = 0.f;
    if (t <= 5) {
        float pC = zp[(size_t)((t + 2) * BB + b) * GG + tid];
        float s02 = pC - pAc;
        float sim = 1.f - s02 * s02;
        float d2 = pC - pBc, d0 = pAc - pBc;
        pres = sim * (d2 * d2 + d0 * d0);
    }

    // ---- block reduce 7 scalars -> private ws slot (no atomics) ----
    float r[7] = {zdiff, pres, poolc, obj, fsq, szp, sflow};
    int w = tid >> 6, lane = tid & 63;
#pragma unroll
    for (int j = 0; j < 7; j++) {
        float rv = wred(r[j]);
        if (lane == 0) bred[j][w] = rv;
    }
    __syncthreads();
    if (tid < 7)
        ws[pairIdx * 8 + tid] = bred[tid][0] + bred[tid][1] + bred[tid][2] + bred[tid][3];
}

__global__ __launch_bounds__(256) void final_kernel(const float* __restrict__ ws,
                                                    const int* __restrict__ gs,
                                                    float* __restrict__ out) {
    const int tid = threadIdx.x;
    __shared__ float bred[7][4];
    float c[7] = {0.f, 0.f, 0.f, 0.f, 0.f, 0.f, 0.f};
    for (int p = tid; p < (TT - 1) * BB; p += 256) {
        const float* r = ws + p * 8;
#pragma unroll
        for (int j = 0; j < 7; j++) c[j] += r[j];
    }
    int w = tid >> 6, lane = tid & 63;
#pragma unroll
    for (int j = 0; j < 7; j++) {
        float rv = wred(c[j]);
        if (lane == 0) bred[j][w] = rv;
    }
    __syncthreads();
    if (tid == 0) {
        float s[7];
#pragma unroll
        for (int j = 0; j < 7; j++) s[j] = bred[j][0] + bred[j][1] + bred[j][2] + bred[j][3];
        float step = (float)gs[0];
        float scale_obj = fminf(1.f, step / 200000.f);
        float scale_flow = fmaxf(0.f, 1.f - step / 100000.f);
        float flow_loss = s[4] + 100.f * fmaxf(0.f, s[5] - s[6]);
        out[0] = s[0]                       // z_what_loss * ADJ_W
               + s[1]                       // z_pres_loss * PRES_W
               + s[2]                       // pool (already negated) * POOL_W
               + s[3] * scale_obj * 10.0f   // objects * OBJ_W
               + flow_loss * scale_flow;    // FLOW_W = 1
    }
}

extern "C" void kernel_launch(void* const* d_in, const int* in_sizes, int n_in,
                              void* d_out, int out_size, void* d_ws, size_t ws_size,
                              hipStream_t stream) {
    const float* zw = (const float*)d_in[0];
    const float* zp = (const float*)d_in[1];
    const float* fl = (const float*)d_in[2];
    const int* gs = (const int*)d_in[3];
    float* ws = (float*)d_ws;

    pair_kernel<<<(TT - 1) * BB, 256, 0, stream>>>(zw, zp, fl, ws);
    final_kernel<<<1, 256, 0, stream>>>(ws, gs, (float*)d_out);
}

// Round 7
// 132.347 us; speedup vs baseline: 1.1537x; 1.1537x over previous
//
#include <hip/hip_runtime.h>
#include <math.h>

// Problem constants
#define TT 8
#define BB 128
#define GG 256
#define DD 64
#define NCH 4     // D chunks
#define CF4 4     // float4s per cell per chunk (16 floats)
#define ST 5      // padded LDS stride in float4s -- MEASURED zero-conflict (rounds 0,4,6).
                  // Round-5 lesson: do NOT replace with derived swizzles (XOR-q "perfect
                  // spread" measured 2.24M conflicts). Trust the measured layout.

// ws layout: ws[pair*8 + c], c: 0 zdiff, 1 pres, 2 poolc(neg), 3 obj,
//                               4 flow_sq, 5 sum(zp), 6 sum(flow), 7 unused
// Round-2 lesson: contended device atomics in the block epilogue cost ~15 us;
// private ws slots + 1-block final_kernel is strictly better.

__device__ inline float wred(float v) {
#pragma unroll
    for (int off = 32; off > 0; off >>= 1) v += __shfl_xor(v, off, 64);
    return v;
}
__device__ inline float dot4(float4 a, float4 b) {
    return a.x * b.x + a.y * b.y + a.z * b.z + a.w * b.w;
}
__device__ inline float4 fabs4(float4 a) {
    return make_float4(fabsf(a.x), fabsf(a.y), fabsf(a.z), fabsf(a.w));
}
__device__ inline float4 max4(float4 a, float4 b) {
    return make_float4(fmaxf(a.x, b.x), fmaxf(a.y, b.y), fmaxf(a.z, b.z), fmaxf(a.w, b.w));
}
__device__ inline float4 scale4(float4 a, float s) {
    return make_float4(a.x * s, a.y * s, a.z * s, a.w * s);
}
__device__ inline float4 sub4(float4 a, float4 b) {
    return make_float4(a.x - b.x, a.y - b.y, a.z - b.z, a.w - b.w);
}

// ---- DPP row rotations (16-lane rows == grid rows, since cell == tid) ----
// ROW_ROR:N rotates within each 16-lane row WITH wraparound == jnp.roll on gj.
// Direction convention made irrelevant by construction: the neighbor COLUMN INDEX
// is computed by applying the same rotation to gj itself, so every rotated dot is
// paired with the matching neighbor's norm/presence. NUMERICALLY VERIFIED round 6.
#define DPP_ROR1  0x121
#define DPP_ROR15 0x12F
template <int CTRL>
__device__ inline int dppi(int v) {
    return __builtin_amdgcn_update_dpp(v, v, CTRL, 0xF, 0xF, false);
}
template <int CTRL>
__device__ inline float dppf(float v) {
    return __int_as_float(dppi<CTRL>(__float_as_int(v)));
}
template <int CTRL>
__device__ inline float4 dpp4(float4 v) {
    return make_float4(dppf<CTRL>(v.x), dppf<CTRL>(v.y), dppf<CTRL>(v.z), dppf<CTRL>(v.w));
}

// 3-wide clamped row max via DPP (verified rounds 1-6). old = v, bound_ctrl=false
// -> out-of-row lanes get v (identity for max): clamped semantics for free.
__device__ inline float rowmax3(float v) {
    int iv = __float_as_int(v);
    int a = __builtin_amdgcn_update_dpp(iv, iv, 0x101, 0xF, 0xF, false); // row_shl:1
    int c = __builtin_amdgcn_update_dpp(iv, iv, 0x111, 0xF, 0xF, false); // row_shr:1
    return fmaxf(v, fmaxf(__int_as_float(a), __int_as_float(c)));
}
__device__ inline float4 rowmax3_4(float4 v) {
    return make_float4(rowmax3(v.x), rowmax3(v.y), rowmax3(v.z), rowmax3(v.w));
}

// VGPR discipline (rounds 1/3/5/6): the 128-VGPR cliff costs ~24 us (three >128
// kernels all landed 65-67 us). Round-7 live-range diet: rm dies at its shM store
// (colmax reloads own row-max), aB dies at the barrier (pool reloads raw B from
// shB), and the aA-consuming dots phase completes before the sm[] transient so the
// two 16-reg sets never coexist. Costs +8 LDS reads/chunk; total LDS ops/chunk
// still drop 64 (R4) -> 32.
__global__ __launch_bounds__(256) void pair_kernel(const float* __restrict__ zw,
                                                   const float* __restrict__ zp,
                                                   const float* __restrict__ flow,
                                                   float* __restrict__ ws) {
    const int pairIdx = blockIdx.x;            // 0 .. 7*BB-1
    const int t = pairIdx >> 7;                // BB = 128
    const int b = pairIdx & (BB - 1);
    const int tid = threadIdx.x;
    const int gi = tid >> 4, gj = tid & 15;

    __shared__ float4 shB[GG * ST];            // raw B chunk (up/down rows + pool reload)
    __shared__ float4 shM[GG * ST];            // row-max chunk (col-max pass)
    __shared__ float pA[GG], pB[GG], nrmB[GG];
    __shared__ float bred[7][4];

    const float4* gA = (const float4*)zw + (size_t)(t * BB + b) * 1024;
    const float4* gB = gA + (size_t)BB * 1024;

    const float pAc = zp[(size_t)(t * BB + b) * GG + tid];
    const float pBc = zp[(size_t)((t + 1) * BB + b) * GG + tid];
    pA[tid] = pAc;                             // visibility covered by chunk-loop syncs
    pB[tid] = pBc;

    // neighbor columns, derived with the SAME rotations as the data (direction-proof)
    const int ncol1 = dppi<DPP_ROR1>(gj);
    const int ncol2 = dppi<DPP_ROR15>(gj);
    const int rowU = ((gi - 1) & 15) << 4;     // wrapped up-row base cell
    const int rowD = ((gi + 1) & 15) << 4;     // wrapped down-row base cell
    const int baseU = (rowU + gj) * ST;
    const int baseD = (rowD + gj) * ST;

    // dots d<r><c>: r 0=up,1=center,2=down ; c 0=own col, 1=ror1 col, 2=ror15 col
    float d00 = 0.f, d01 = 0.f, d02 = 0.f;
    float d10 = 0.f, d11 = 0.f, d12 = 0.f;
    float d20 = 0.f, d21 = 0.f, d22 = 0.f;
    float zdiff = 0.f, sa = 0.f, sb = 0.f, poolDot = 0.f, poolN = 0.f;
    const int sbase = tid * ST;

    // IMPORTANT: unroll 1 -- full unroll hoists all chunks' global loads and spills.
#pragma unroll 1
    for (int c = 0; c < NCH; c++) {
        float4 aA[CF4], aB[CF4];
#pragma unroll
        for (int q = 0; q < CF4; q++) {
            aA[q] = gA[tid * 16 + c * 4 + q];
            aB[q] = gB[tid * 16 + c * 4 + q];
        }

        // stage raw B and DPP row-max; rm is a per-q transient (dies at its store)
#pragma unroll
        for (int q = 0; q < CF4; q++) {
            shB[sbase + q] = aB[q];
            shM[sbase + q] = rowmax3_4(scale4(fabs4(aA[q]), pAc));
        }
        // center row entirely from registers: stats + 3 dots; aB dies here
#pragma unroll
        for (int q = 0; q < CF4; q++) {
            float4 d = sub4(aB[q], aA[q]);
            zdiff += dot4(d, d);
            sa += dot4(aA[q], aA[q]);
            sb += dot4(aB[q], aB[q]);
            d10 += dot4(aA[q], aB[q]);
            d11 += dot4(aA[q], dpp4<DPP_ROR1>(aB[q]));
            d12 += dot4(aA[q], dpp4<DPP_ROR15>(aB[q]));
        }
        __syncthreads();

        // up/down rows: ONE LDS read each per q, columns via DPP; aA dies here
#pragma unroll
        for (int q = 0; q < CF4; q++) {
            float4 bu = shB[baseU + q];
            d00 += dot4(aA[q], bu);
            d01 += dot4(aA[q], dpp4<DPP_ROR1>(bu));
            d02 += dot4(aA[q], dpp4<DPP_ROR15>(bu));
            float4 bd = shB[baseD + q];
            d20 += dot4(aA[q], bd);
            d21 += dot4(aA[q], dpp4<DPP_ROR1>(bd));
            d22 += dot4(aA[q], dpp4<DPP_ROR15>(bd));
        }
        // clamped col-max: reload own row-max from shM (no cross-barrier rm regs),
        // pool B term reloaded from shB (no cross-barrier aB regs)
        {
            float4 sm[CF4];
#pragma unroll
            for (int q = 0; q < CF4; q++) sm[q] = shM[sbase + q];
            if (gi > 0) {
#pragma unroll
                for (int q = 0; q < CF4; q++) sm[q] = max4(sm[q], shM[sbase - 16 * ST + q]);
            }
            if (gi < 15) {
#pragma unroll
                for (int q = 0; q < CF4; q++) sm[q] = max4(sm[q], shM[sbase + 16 * ST + q]);
            }
#pragma unroll
            for (int q = 0; q < CF4; q++) {
                poolDot += dot4(sm[q], fabs4(shB[sbase + q]));
                poolN += dot4(sm[q], sm[q]);
            }
        }
        __syncthreads();   // all reads of shB/shM done before next chunk's stores
    }

    // ---- epilogues ----
    nrmB[tid] = sqrtf(sb);
    __syncthreads();

    // objects: 9 (dot, neighbor-cell) pairs, pairing guaranteed by shared rotations
    const int gcol = gi << 4;
    const int ncell[9] = {rowU + gj, rowU + ncol1, rowU + ncol2,
                          tid,       gcol + ncol1, gcol + ncol2,
                          rowD + gj, rowD + ncol1, rowD + ncol2};
    const float dval[9] = {d00, d01, d02, d10, d11, d12, d20, d21, d22};
    float prior_n = fmaxf(sqrtf(sa), 1e-8f);
    float sum_sim = 0.f, max_sim = -1e30f;
    bool has = false;
#pragma unroll
    for (int k = 0; k < 9; k++) {
        float nn = fmaxf(nrmB[ncell[k]], 1e-8f);
        float s = dval[k] / (prior_n * nn);
        if (pB[ncell[k]] > 0.5f) {
            sum_sim += s;
            max_sim = fmaxf(max_sim, s);
            has = true;
        }
    }
    float obj = ((pAc > 0.5f) && has) ? (sum_sim - 5.0f * max_sim) : 0.f;

    // pool
    float na_pool = fmaxf(sqrtf(poolN), 1e-6f);
    float nb_pool = fmaxf(pBc * sqrtf(sb), 1e-6f);
    float poolc = -(pBc * poolDot) / (na_pool * nb_pool) * 0.5f * (pAc + pBc);

    // flow (image t; block t=6 also handles image 7): clamped 3x3 max of zp
    float mx = pAc;
#pragma unroll
    for (int di = -1; di <= 1; di++)
#pragma unroll
        for (int dj = -1; dj <= 1; dj++) {
            if (di == 0 && dj == 0) continue;
            int ni = gi + di, nj = gj + dj;
            if (((unsigned)ni < 16u) && ((unsigned)nj < 16u))
                mx = fmaxf(mx, pA[(ni << 4) + nj]);
        }
    float f = flow[(size_t)(t * BB + b) * GG + tid];
    float fsq = 0.f;
    if (f > 0.5f) { float d = mx - f; fsq = d * d; }
    float szp = pAc, sflow = f;
    if (t == 6) {
        float mxB = pBc;
#pragma unroll
        for (int di = -1; di <= 1; di++)
#pragma unroll
            for (int dj = -1; dj <= 1; dj++) {
                if (di == 0 && dj == 0) continue;
                int ni = gi + di, nj = gj + dj;
                if (((unsigned)ni < 16u) && ((unsigned)nj < 16u))
                    mxB = fmaxf(mxB, pB[(ni << 4) + nj]);
            }
        float f7 = flow[(size_t)(7 * BB + b) * GG + tid];
        if (f7 > 0.5f) { float d = mxB - f7; fsq += d * d; }
        szp += pBc;
        sflow += f7;
    }

    // pres triple (t, t+1, t+2) for t <= 5
    float pres = 0.f;
    if (t <= 5) {
        float pC = zp[(size_t)((t + 2) * BB + b) * GG + tid];
        float s02 = pC - pAc;
        float sim = 1.f - s02 * s02;
        float d2 = pC - pBc, d0 = pAc - pBc;
        pres = sim * (d2 * d2 + d0 * d0);
    }

    // ---- block reduce 7 scalars -> private ws slot (no atomics) ----
    float r[7] = {zdiff, pres, poolc, obj, fsq, szp, sflow};
    int w = tid >> 6, lane = tid & 63;
#pragma unroll
    for (int j = 0; j < 7; j++) {
        float rv = wred(r[j]);
        if (lane == 0) bred[j][w] = rv;
    }
    __syncthreads();
    if (tid < 7)
        ws[pairIdx * 8 + tid] = bred[tid][0] + bred[tid][1] + bred[tid][2] + bred[tid][3];
}

__global__ __launch_bounds__(256) void final_kernel(const float* __restrict__ ws,
                                                    const int* __restrict__ gs,
                                                    float* __restrict__ out) {
    const int tid = threadIdx.x;
    __shared__ float bred[7][4];
    float c[7] = {0.f, 0.f, 0.f, 0.f, 0.f, 0.f, 0.f};
    for (int p = tid; p < (TT - 1) * BB; p += 256) {
        const float* r = ws + p * 8;
#pragma unroll
        for (int j = 0; j < 7; j++) c[j] += r[j];
    }
    int w = tid >> 6, lane = tid & 63;
#pragma unroll
    for (int j = 0; j < 7; j++) {
        float rv = wred(c[j]);
        if (lane == 0) bred[j][w] = rv;
    }
    __syncthreads();
    if (tid == 0) {
        float s[7];
#pragma unroll
        for (int j = 0; j < 7; j++) s[j] = bred[j][0] + bred[j][1] + bred[j][2] + bred[j][3];
        float step = (float)gs[0];
        float scale_obj = fminf(1.f, step / 200000.f);
        float scale_flow = fmaxf(0.f, 1.f - step / 100000.f);
        float flow_loss = s[4] + 100.f * fmaxf(0.f, s[5] - s[6]);
        out[0] = s[0]                       // z_what_loss * ADJ_W
               + s[1]                       // z_pres_loss * PRES_W
               + s[2]                       // pool (already negated) * POOL_W
               + s[3] * scale_obj * 10.0f   // objects * OBJ_W
               + flow_loss * scale_flow;    // FLOW_W = 1
    }
}

extern "C" void kernel_launch(void* const* d_in, const int* in_sizes, int n_in,
                              void* d_out, int out_size, void* d_ws, size_t ws_size,
                              hipStream_t stream) {
    const float* zw = (const float*)d_in[0];
    const float* zp = (const float*)d_in[1];
    const float* fl = (const float*)d_in[2];
    const int* gs = (const int*)d_in[3];
    float* ws = (float*)d_ws;

    pair_kernel<<<(TT - 1) * BB, 256, 0, stream>>>(zw, zp, fl, ws);
    final_kernel<<<1, 256, 0, stream>>>(ws, gs, (float*)d_out);
}